// Round 8
// baseline (121.120 us; speedup 1.0000x reference)
//
#include <hip/hip_runtime.h>
#include <hip/hip_bf16.h>
#include <cstdint>

#define BATCH 8
#define NREP 12306          // N
#define OUTC 192            // TS^3*3

typedef float floatx4 __attribute__((ext_vector_type(4)));   // native vector for nontemporal builtin

__device__ __forceinline__ float gelu_exact(float x) {
    return 0.5f * x * (1.0f + erff(x * 0.70710678118654752f));
}
__device__ __forceinline__ float sigmoidf_(float x) {
    return 1.0f / (1.0f + __expf(-x));
}

// Wave-per-row GEMV over 8 batches. block = 256 = 4 waves, 1 row/wave.
template <int K, int R, int ACT>
__global__ __launch_bounds__(256) void gemv_layer(const float* __restrict__ in,
                                                  const float* __restrict__ W,
                                                  const float* __restrict__ bias,
                                                  float* __restrict__ out) {
    const int wave = threadIdx.x >> 6;
    const int lane = threadIdx.x & 63;
    const int row  = blockIdx.x * 4 + wave;
    if (row >= R) return;

    constexpr int NV = K / 256;  // float4 loads per lane
    float4 wv[NV];
    const float4* Wrow = reinterpret_cast<const float4*>(W + (size_t)row * K);
#pragma unroll
    for (int i = 0; i < NV; ++i) wv[i] = Wrow[i * 64 + lane];

    float acc[BATCH];
#pragma unroll
    for (int b = 0; b < BATCH; ++b) {
        const float4* ib = reinterpret_cast<const float4*>(in + b * K);
        float a = 0.0f;
#pragma unroll
        for (int i = 0; i < NV; ++i) {
            const float4 iv = ib[i * 64 + lane];
            a = fmaf(wv[i].x, iv.x, a);
            a = fmaf(wv[i].y, iv.y, a);
            a = fmaf(wv[i].z, iv.z, a);
            a = fmaf(wv[i].w, iv.w, a);
        }
        acc[b] = a;
    }
#pragma unroll
    for (int b = 0; b < BATCH; ++b) {
#pragma unroll
        for (int s = 32; s > 0; s >>= 1) acc[b] += __shfl_xor(acc[b], s, 64);
    }
    if (lane == 0) {
        const float bb = bias[row];
#pragma unroll
        for (int b = 0; b < BATCH; ++b) {
            const float x = acc[b] + bb;
            out[b * R + row] = (ACT == 0) ? gelu_exact(x) : sigmoidf_(x);
        }
    }
}

// 768 blocks x 512 threads; each block handles 2 (b,p) runs, one per
// wave-half (waves 0-3 -> run 0, waves 4-7 -> run 1). Dot computed
// redundantly in each wave (butterfly leaves sum in all lanes) — no LDS,
// no syncthreads. Stores are nontemporal (write-once stream, never re-read).
__global__ __launch_bounds__(512) void l4_broadcast(const float* __restrict__ h3,
                                                    const float* __restrict__ W4,
                                                    const float* __restrict__ b4,
                                                    float* __restrict__ out) {
    const int half = threadIdx.x >> 8;        // 0 or 1
    const int bp   = blockIdx.x * 2 + half;   // 0 .. 1535
    const int b    = bp / OUTC;
    const int p    = bp - b * OUTC;
    const int lane = threadIdx.x & 63;

    const float4* hb = reinterpret_cast<const float4*>(h3 + b * 512);
    const float4* wr = reinterpret_cast<const float4*>(W4 + (size_t)p * 512);
    float a = 0.0f;
#pragma unroll
    for (int i = 0; i < 2; ++i) {
        const float4 x = hb[i * 64 + lane];
        const float4 w = wr[i * 64 + lane];
        a = fmaf(x.x, w.x, a); a = fmaf(x.y, w.y, a);
        a = fmaf(x.z, w.z, a); a = fmaf(x.w, w.w, a);
    }
#pragma unroll
    for (int s = 32; s > 0; s >>= 1) a += __shfl_xor(a, s, 64);
    const float v = sigmoidf_(a + b4[p]);     // identical in all lanes

    const size_t e0 = (size_t)bp * NREP;
    float* ptr = out + e0;
    const int t = threadIdx.x & 255;          // 0..255 within the half
    const int mis  = (int)(e0 & 3);
    const int head = mis ? (4 - mis) : 0;
    if (t < head) ptr[t] = v;
    const int n4 = (NREP - head) >> 2;
    const floatx4 vv = {v, v, v, v};
    floatx4* p4 = reinterpret_cast<floatx4*>(ptr + head);
    for (int i = t; i < n4; i += 256) __builtin_nontemporal_store(vv, &p4[i]);
    const int done = head + (n4 << 2);
    if (t < NREP - done) ptr[done + t] = v;
}

extern "C" void kernel_launch(void* const* d_in, const int* in_sizes, int n_in,
                              void* d_out, int out_size, void* d_ws, size_t ws_size,
                              hipStream_t stream) {
    const float* latent = (const float*)d_in[0];
    const float* W1 = (const float*)d_in[1];
    const float* b1 = (const float*)d_in[2];
    const float* W2 = (const float*)d_in[3];
    const float* b2 = (const float*)d_in[4];
    const float* W3 = (const float*)d_in[5];
    const float* b3 = (const float*)d_in[6];
    const float* W4 = (const float*)d_in[7];
    const float* b4 = (const float*)d_in[8];
    float* out = (float*)d_out;

    float* ws = (float*)d_ws;
    float* h1 = ws;                        // 8*512
    float* h2 = h1 + BATCH * 512;          // 8*1024
    float* h3 = h2 + BATCH * 1024;         // 8*512

    gemv_layer< 256,  512, 0><<<128, 256, 0, stream>>>(latent, W1, b1, h1);
    gemv_layer< 512, 1024, 0><<<256, 256, 0, stream>>>(h1,     W2, b2, h2);
    gemv_layer<1024,  512, 0><<<128, 256, 0, stream>>>(h2,     W3, b3, h3);
    l4_broadcast<<<(BATCH * OUTC) / 2, 512, 0, stream>>>(h3, W4, b4, out);
}

// Round 9
// 113.474 us; speedup vs baseline: 1.0674x; 1.0674x over previous
//
#include <hip/hip_runtime.h>
#include <hip/hip_bf16.h>
#include <cstdint>

#define BATCH 8
#define NREP 12306          // N
#define OUTC 192            // TS^3*3

__device__ __forceinline__ float gelu_exact(float x) {
    return 0.5f * x * (1.0f + erff(x * 0.70710678118654752f));
}
__device__ __forceinline__ float sigmoidf_(float x) {
    return 1.0f / (1.0f + __expf(-x));
}

// Wave-per-row GEMV over 8 batches. block = 256 = 4 waves, 1 row/wave.
template <int K, int R, int ACT>
__global__ __launch_bounds__(256) void gemv_layer(const float* __restrict__ in,
                                                  const float* __restrict__ W,
                                                  const float* __restrict__ bias,
                                                  float* __restrict__ out) {
    const int wave = threadIdx.x >> 6;
    const int lane = threadIdx.x & 63;
    const int row  = blockIdx.x * 4 + wave;
    if (row >= R) return;

    constexpr int NV = K / 256;  // float4 loads per lane
    float4 wv[NV];
    const float4* Wrow = reinterpret_cast<const float4*>(W + (size_t)row * K);
#pragma unroll
    for (int i = 0; i < NV; ++i) wv[i] = Wrow[i * 64 + lane];

    float acc[BATCH];
#pragma unroll
    for (int b = 0; b < BATCH; ++b) {
        const float4* ib = reinterpret_cast<const float4*>(in + b * K);
        float a = 0.0f;
#pragma unroll
        for (int i = 0; i < NV; ++i) {
            const float4 iv = ib[i * 64 + lane];
            a = fmaf(wv[i].x, iv.x, a);
            a = fmaf(wv[i].y, iv.y, a);
            a = fmaf(wv[i].z, iv.z, a);
            a = fmaf(wv[i].w, iv.w, a);
        }
        acc[b] = a;
    }
#pragma unroll
    for (int b = 0; b < BATCH; ++b) {
#pragma unroll
        for (int s = 32; s > 0; s >>= 1) acc[b] += __shfl_xor(acc[b], s, 64);
    }
    if (lane == 0) {
        const float bb = bias[row];
#pragma unroll
        for (int b = 0; b < BATCH; ++b) {
            const float x = acc[b] + bb;
            out[b * R + row] = (ACT == 0) ? gelu_exact(x) : sigmoidf_(x);
        }
    }
}

// One block per (b,p) run: compute o[b][p] = sigmoid(W4[p]·h3[b] + b4[p])
// redundantly in every wave (butterfly reduce leaves the sum in all lanes),
// then stream NREP copies with aligned float4 stores. No LDS, no syncthreads.
__global__ __launch_bounds__(256) void l4_broadcast(const float* __restrict__ h3,
                                                    const float* __restrict__ W4,
                                                    const float* __restrict__ b4,
                                                    float* __restrict__ out) {
    const int bp = blockIdx.x;           // 0 .. 1535
    const int b  = bp / OUTC;
    const int p  = bp - b * OUTC;
    const int lane = threadIdx.x & 63;

    const float4* hb = reinterpret_cast<const float4*>(h3 + b * 512);
    const float4* wr = reinterpret_cast<const float4*>(W4 + (size_t)p * 512);
    float a = 0.0f;
#pragma unroll
    for (int i = 0; i < 2; ++i) {
        const float4 x = hb[i * 64 + lane];
        const float4 w = wr[i * 64 + lane];
        a = fmaf(x.x, w.x, a); a = fmaf(x.y, w.y, a);
        a = fmaf(x.z, w.z, a); a = fmaf(x.w, w.w, a);
    }
#pragma unroll
    for (int s = 32; s > 0; s >>= 1) a += __shfl_xor(a, s, 64);
    const float v = sigmoidf_(a + b4[p]);   // identical in all lanes

    const size_t e0 = (size_t)bp * NREP;
    float* ptr = out + e0;
    const int t = threadIdx.x;
    const int mis  = (int)(e0 & 3);
    const int head = mis ? (4 - mis) : 0;
    if (t < head) ptr[t] = v;
    const int n4 = (NREP - head) >> 2;
    const float4 vv = make_float4(v, v, v, v);
    float4* p4 = reinterpret_cast<float4*>(ptr + head);
    for (int i = t; i < n4; i += 256) p4[i] = vv;
    const int done = head + (n4 << 2);
    if (t < NREP - done) ptr[done + t] = v;
}

extern "C" void kernel_launch(void* const* d_in, const int* in_sizes, int n_in,
                              void* d_out, int out_size, void* d_ws, size_t ws_size,
                              hipStream_t stream) {
    const float* latent = (const float*)d_in[0];
    const float* W1 = (const float*)d_in[1];
    const float* b1 = (const float*)d_in[2];
    const float* W2 = (const float*)d_in[3];
    const float* b2 = (const float*)d_in[4];
    const float* W3 = (const float*)d_in[5];
    const float* b3 = (const float*)d_in[6];
    const float* W4 = (const float*)d_in[7];
    const float* b4 = (const float*)d_in[8];
    float* out = (float*)d_out;

    float* ws = (float*)d_ws;
    float* h1 = ws;                        // 8*512
    float* h2 = h1 + BATCH * 512;          // 8*1024
    float* h3 = h2 + BATCH * 1024;         // 8*512

    gemv_layer< 256,  512, 0><<<128, 256, 0, stream>>>(latent, W1, b1, h1);
    gemv_layer< 512, 1024, 0><<<256, 256, 0, stream>>>(h1,     W2, b2, h2);
    gemv_layer<1024,  512, 0><<<128, 256, 0, stream>>>(h2,     W3, b3, h3);
    l4_broadcast<<<BATCH * OUTC, 256, 0, stream>>>(h3, W4, b4, out);
}